// Round 7
// baseline (1045.432 us; speedup 1.0000x reference)
//
#include <hip/hip_runtime.h>
#include <hip/hip_bf16.h>
#include <cstdint>
#include <cstddef>

#define N 4096
#define NN ((size_t)N * (size_t)N)

typedef int   int4v   __attribute__((ext_vector_type(4)));
typedef float float4v __attribute__((ext_vector_type(4)));

__device__ inline void async16(const void* g, void* lds) {
    __builtin_amdgcn_global_load_lds(
        (const __attribute__((address_space(1))) void*)g,
        (__attribute__((address_space(3))) void*)lds, 16, 0, 0);
}

// SWAR per-byte abs for packed i8 (valid for byte values in [-4,3], ours are [-2,2]):
// s = 0x01 per negative byte; m = 0xFF per negative byte; |v| = (v^m)+s.
// No cross-byte carries since (v^m) <= 0x01 on negative bytes here.
__device__ inline unsigned absb4(unsigned v) {
    unsigned s = (v >> 7) & 0x01010101u;
    unsigned m = s * 255u;
    return (v ^ m) + s;
}
__device__ inline int4v absfrag(int4v v) {
    int4v r;
    r[0] = (int)absb4((unsigned)v[0]);
    r[1] = (int)absb4((unsigned)v[1]);
    r[2] = (int)absb4((unsigned)v[2]);
    r[3] = (int)absb4((unsigned)v[3]);
    return r;
}

// ---------------- kernel 1: FUSED mod + diag + build (A, AT only) ----------------
// Block owns the unordered tile pair {(I,J),(J,I)}, I<=J.  512 threads: half = t>>8
// selects the tile.  NEW: (a) no Aa/ATa outputs (gemm derives |A| in-register);
// (b) all 12 float4 loads issued before any dependent store (memory ILP).
// All expressions keep the proven operand order:  A[r][c] = mod[r][c] + mod[c][r]
// - d[c];  mod = fmaf(hard, -2o, o), hard = (p+u >= 1)  [bit-exact].
__global__ __launch_bounds__(512) void fused_mod_build(
        const float* __restrict__ ori,
        const float* __restrict__ clp,
        const float* __restrict__ uu,
        float* __restrict__ out,
        signed char* __restrict__ A,
        signed char* __restrict__ AT,
        double* __restrict__ accs) {
    const int I = blockIdx.x, J = blockIdx.y;
    if (I > J) return;
    __shared__ float sm1[64][65];   // sm1[i][j] = mod[bi+i][bj+j]
    __shared__ float sm2[64][65];   // sm2[j][i] = mod[bj+j][bi+i]
    __shared__ float dI[64], dJ[64];
    const int t    = threadIdx.x;   // 0..511
    const int half = t >> 8;        // 0: tile (I,J); 1: tile (J,I)
    const int tt   = t & 255;
    const int r    = tt >> 2;       // 0..63
    const int q    = tt & 3;        // 0..3 (16-col group)
    const int bi = I * 64, bj = J * 64;
    if (I == 0 && J == 0 && t < 2) accs[t] = 0.0;
    if (t < 128) {
        const int x = (t < 64) ? (bi + t) : (bj + (t - 64));
        const size_t off = (size_t)x * N + x;
        const float o = ori[off];
        const float hard = (clp[off] + uu[off] >= 1.0f) ? 1.0f : 0.0f;
        const float d = fmaf(hard, -2.0f * o, o);
        if (t < 64) dI[t] = d; else dJ[t - 64] = d;
    }
    // load phase: each half loads its own tile; all 12 loads in flight first
    {
        const int rowbase = half ? bj : bi;
        const int colbase = half ? bi : bj;
        float (*sm)[65] = half ? sm2 : sm1;
        const bool wr = (half == 0) || (I != J);   // skip duplicate out-write on diagonal
        float4v o4[4], p4[4], u4[4];
        #pragma unroll
        for (int k = 0; k < 4; ++k) {
            const size_t off = (size_t)(rowbase + r) * N + colbase + k * 16 + q * 4;
            o4[k] = *(const float4v*)(ori + off);
        }
        #pragma unroll
        for (int k = 0; k < 4; ++k) {
            const size_t off = (size_t)(rowbase + r) * N + colbase + k * 16 + q * 4;
            p4[k] = *(const float4v*)(clp + off);
        }
        #pragma unroll
        for (int k = 0; k < 4; ++k) {
            const size_t off = (size_t)(rowbase + r) * N + colbase + k * 16 + q * 4;
            u4[k] = *(const float4v*)(uu + off);
        }
        #pragma unroll
        for (int k = 0; k < 4; ++k) {
            float4v m;
            #pragma unroll
            for (int c = 0; c < 4; ++c) {
                const float hard = (p4[k][c] + u4[k][c] >= 1.0f) ? 1.0f : 0.0f;
                m[c] = fmaf(hard, -2.0f * o4[k][c], o4[k][c]);
                sm[r][k * 16 + q * 4 + c] = m[c];
            }
            if (wr) {
                const size_t off = (size_t)(rowbase + r) * N + colbase + k * 16 + q * 4;
                *(float4v*)(out + off) = m;
            }
        }
    }
    __syncthreads();
    // pack phase: half 0 emits A(I,J) + AT(J,I); half 1 emits A(J,I) + AT(I,J)
    if (half == 0) {
        int pkA1[4], pkT1[4];
        #pragma unroll
        for (int w = 0; w < 4; ++w) {
            int a1w = 0, t1w = 0;
            #pragma unroll
            for (int k = 0; k < 4; ++k) {
                const int c = q * 16 + w * 4 + k;
                // A tile (I,J): mod[bi+r][bj+c] + mod[bj+c][bi+r] - d[bj+c]
                const float a1 = sm1[r][c] + sm2[c][r] - dJ[c];
                const int v1 = (int)a1;
                a1w |= (v1 & 255) << (8 * k);
                // AT tile (J,I): A[bi+c][bj+r] = mod[bi+c][bj+r]+mod[bj+r][bi+c]-d[bj+r]
                const float t1 = sm1[c][r] + sm2[r][c] - dJ[r];
                const int w1 = (int)t1;
                t1w |= (w1 & 255) << (8 * k);
            }
            pkA1[w] = a1w; pkT1[w] = t1w;
        }
        const size_t oIJ = (size_t)(bi + r) * N + bj + q * 16;
        const size_t oJI = (size_t)(bj + r) * N + bi + q * 16;
        *(int4v*)&A [oIJ] = *(int4v*)pkA1;
        *(int4v*)&AT[oJI] = *(int4v*)pkT1;
    } else if (I != J) {
        int pkA2[4], pkT2[4];
        #pragma unroll
        for (int w = 0; w < 4; ++w) {
            int a2w = 0, t2w = 0;
            #pragma unroll
            for (int k = 0; k < 4; ++k) {
                const int c = q * 16 + w * 4 + k;
                // A tile (J,I): mod[bj+r][bi+c] + mod[bi+c][bj+r] - d[bi+c]
                const float a2 = sm2[r][c] + sm1[c][r] - dI[c];
                const int v2 = (int)a2;
                a2w |= (v2 & 255) << (8 * k);
                // AT tile (I,J): A[bj+c][bi+r] = mod[bj+c][bi+r]+mod[bi+r][bj+c]-d[bi+r]
                const float t2 = sm2[c][r] + sm1[r][c] - dI[r];
                const int w2 = (int)t2;
                t2w |= (w2 & 255) << (8 * k);
            }
            pkA2[w] = a2w; pkT2[w] = t2w;
        }
        const size_t oIJ = (size_t)(bi + r) * N + bj + q * 16;
        const size_t oJI = (size_t)(bj + r) * N + bi + q * 16;
        *(int4v*)&A [oJI] = *(int4v*)pkA2;
        *(int4v*)&AT[oIJ] = *(int4v*)pkT2;
    }
}

// ---------------- kernel 4: i8 GEMM-trace, BOTH traces from one staging pass ----------
// accs[0] = tr((A.A).A), accs[1] = tr((|A|.|A|).|A|).  |A| fragments are derived
// in-register via SWAR byte-abs (|A^T| == |A|^T exactly).  Staging, swizzle, and
// the proven one-barrier-per-K-tile counted-vmcnt schedule are unchanged; per tile
// the MFMA count doubles (32 A + 32 |A|) while LDS reads and global fetch stay the
// same as ONE of the old z-slices — halving total memory-system load.
#define BK 64
#define NT (N / BK)      // 64 K-tiles
#define BUFSZ 32768      // A 16K + B 16K per buffer

__global__ __launch_bounds__(512, 1) void gemm_trace_i8(
        const signed char* __restrict__ Ag,
        const signed char* __restrict__ ATg,
        double* __restrict__ accs) {
    __shared__ __align__(16) signed char lds[4 * BUFSZ];   // 128 KiB
    __shared__ int red[8][2];
    const signed char* Asrc = Ag;    // M rows   (i-panel)
    const signed char* Bsrc = ATg;   // MT rows  (k-panel), B[k][n] = MT[n][k]
    const int i0 = blockIdx.y * 256;
    const int k0 = blockIdx.x * 256;
    const int t = threadIdx.x;
    const int lane = t & 63;
    const int wave = t >> 6;        // 0..7
    const int wm = wave >> 2;       // 0..1 -> M offset wm*128
    const int wn = wave & 3;        // 0..3 -> N offset wn*64
    const int quad = lane >> 4;
    const int col  = lane & 15;

    const int c1 = t;
    const int r1 = c1 >> 2;          // 0..127
    const int r2 = r1 + 128;
    const int s1 = (((c1 & 3) ^ ((r1 >> 1) & 3)) << 4);
    const int s2 = (((c1 & 3) ^ ((r2 >> 1) & 3)) << 4);
    const signed char* gA1 = Asrc + (size_t)(i0 + r1) * N + s1;
    const signed char* gA2 = Asrc + (size_t)(i0 + r2) * N + s2;
    const signed char* gB1 = Bsrc + (size_t)(k0 + r1) * N + s1;
    const signed char* gB2 = Bsrc + (size_t)(k0 + r2) * N + s2;
    const int ldsA1 = (wave * 64) * 16;           // wave-uniform LDS bases
    const int ldsA2 = 8192  + (wave * 64) * 16;
    const int ldsB1 = 16384 + (wave * 64) * 16;
    const int ldsB2 = 24576 + (wave * 64) * 16;
    const int fsw = ((quad ^ ((col >> 1) & 3)) << 4);  // fragment k-slot after swizzle

    int4v accA[8][4], accB[8][4];
    #pragma unroll
    for (int a = 0; a < 8; ++a)
        #pragma unroll
        for (int b = 0; b < 4; ++b) {
            accA[a][b] = (int4v){0, 0, 0, 0};
            accB[a][b] = (int4v){0, 0, 0, 0};
        }

    for (int p = 0; p < 3; ++p) {
        const int pb = p * BUFSZ;
        const size_t go = (size_t)p * BK;
        async16(gA1 + go, lds + pb + ldsA1);
        async16(gA2 + go, lds + pb + ldsA2);
        async16(gB1 + go, lds + pb + ldsB1);
        async16(gB2 + go, lds + pb + ldsB2);
    }
    asm volatile("s_waitcnt vmcnt(8)" ::: "memory");
    __builtin_amdgcn_s_barrier();
    __builtin_amdgcn_sched_barrier(0);

    for (int j = 0; j < NT; ++j) {
        const int buf = (j & 3) * BUFSZ;
        const signed char* Ab = lds + buf;
        const signed char* Bb = lds + buf + 16384;
        const int pre = j + 3;
        const size_t go = (size_t)pre * BK;
        const int pb = (pre & 3) * BUFSZ;
        int4v af0[4], af1[4], bf[4];
        // issue all 12 fragment reads up front (af0+bf oldest, af1 newest)
        #pragma unroll
        for (int tr = 0; tr < 4; ++tr)
            af0[tr] = *(const int4v*)(Ab + ((wm * 128 + tr * 16 + col) << 6) + fsw);
        #pragma unroll
        for (int tc = 0; tc < 4; ++tc)
            bf[tc] = *(const int4v*)(Bb + ((wn * 64 + tc * 16 + col) << 6) + fsw);
        #pragma unroll
        for (int tr = 0; tr < 4; ++tr)
            af1[tr] = *(const int4v*)(Ab + ((wm * 128 + 64 + tr * 16 + col) << 6) + fsw);
        if (pre < NT) {
            async16(gA1 + go, lds + pb + ldsA1);
            async16(gA2 + go, lds + pb + ldsA2);
            async16(gB1 + go, lds + pb + ldsB1);
            async16(gB2 + go, lds + pb + ldsB2);
        }
        // half 0: wait af0+bf only (8 oldest of 12)
        asm volatile("s_waitcnt lgkmcnt(4)" ::: "memory");
        __builtin_amdgcn_sched_barrier(0);
        __builtin_amdgcn_s_setprio(1);
        {
            int4v ab[4];
            #pragma unroll
            for (int tc = 0; tc < 4; ++tc) ab[tc] = absfrag(bf[tc]);
            #pragma unroll
            for (int tr = 0; tr < 4; ++tr) {
                const int4v aa = absfrag(af0[tr]);
                #pragma unroll
                for (int tc = 0; tc < 4; ++tc) {
                    accA[tr][tc] = __builtin_amdgcn_mfma_i32_16x16x64_i8(af0[tr], bf[tc], accA[tr][tc], 0, 0, 0);
                    accB[tr][tc] = __builtin_amdgcn_mfma_i32_16x16x64_i8(aa,      ab[tc], accB[tr][tc], 0, 0, 0);
                }
            }
            __builtin_amdgcn_s_setprio(0);
            // half 1: af1 completed under the half-0 MFMA cluster
            asm volatile("s_waitcnt lgkmcnt(0)" ::: "memory");
            __builtin_amdgcn_sched_barrier(0);
            __builtin_amdgcn_s_setprio(1);
            #pragma unroll
            for (int tr = 0; tr < 4; ++tr) {
                const int4v aa = absfrag(af1[tr]);
                #pragma unroll
                for (int tc = 0; tc < 4; ++tc) {
                    accA[4 + tr][tc] = __builtin_amdgcn_mfma_i32_16x16x64_i8(af1[tr], bf[tc], accA[4 + tr][tc], 0, 0, 0);
                    accB[4 + tr][tc] = __builtin_amdgcn_mfma_i32_16x16x64_i8(aa,      ab[tc], accB[4 + tr][tc], 0, 0, 0);
                }
            }
        }
        __builtin_amdgcn_s_setprio(0);
        // end-of-tile counted wait: tile j+1's staging landed; single barrier per tile
        if (j < NT - 3)       { asm volatile("s_waitcnt vmcnt(8)" ::: "memory"); }
        else if (j == NT - 3) { asm volatile("s_waitcnt vmcnt(4)" ::: "memory"); }
        else if (j == NT - 2) { asm volatile("s_waitcnt vmcnt(0)" ::: "memory"); }
        __builtin_amdgcn_s_barrier();
        __builtin_amdgcn_sched_barrier(0);
    }

    // trace epilogue: C/D layout col=lane&15, row=quad*4+reg.  Multiplier
    // M[k,i] = Asrc[kk*N + ib + r] (4 consecutive bytes -> one int load);
    // |M| derived via the same SWAR abs.
    int partA = 0, partB = 0;
    #pragma unroll
    for (int mr = 0; mr < 8; ++mr) {
        const int ib = i0 + wm * 128 + mr * 16 + quad * 4;
        #pragma unroll
        for (int tc = 0; tc < 4; ++tc) {
            const int kk = k0 + wn * 64 + tc * 16 + col;
            const unsigned mv = *(const unsigned*)&Asrc[(size_t)kk * N + ib];
            const unsigned av = absb4(mv);
            #pragma unroll
            for (int r = 0; r < 4; ++r) {
                partA += accA[mr][tc][r] * (int)(signed char)(mv >> (8 * r));
                partB += accB[mr][tc][r] * (int)(signed char)(av >> (8 * r));
            }
        }
    }
    #pragma unroll
    for (int off = 32; off > 0; off >>= 1) {
        partA += __shfl_down(partA, off, 64);
        partB += __shfl_down(partB, off, 64);
    }
    if (lane == 0) { red[wave][0] = partA; red[wave][1] = partB; }
    __syncthreads();
    if (t == 0) {
        int totA = 0, totB = 0;
        #pragma unroll
        for (int w = 0; w < 8; ++w) { totA += red[w][0]; totB += red[w][1]; }
        atomicAdd(&accs[0], (double)totA);
        atomicAdd(&accs[1], (double)totB);
    }
}

// ---------------- kernel 5: balance ----------------
__global__ void finalize_kernel(const double* __restrict__ accs, float* __restrict__ out) {
    out[NN] = (float)(0.5 * (1.0 + accs[0] / accs[1]));
}

extern "C" void kernel_launch(void* const* d_in, const int* in_sizes, int n_in,
                              void* d_out, int out_size, void* d_ws, size_t ws_size,
                              hipStream_t stream) {
    const float* ori = (const float*)d_in[0];
    const float* clp = (const float*)d_in[1];
    const float* u   = (const float*)d_in[2];
    float* out = (float*)d_out;
    char* ws = (char*)d_ws;
    signed char* A8  = (signed char*)ws;                    // 16 MiB
    signed char* AT8 = (signed char*)(ws + NN);             // 16 MiB
    double*      accs = (double*)(ws + 2 * NN);             // 16 B

    fused_mod_build<<<dim3(64, 64), 512, 0, stream>>>(
        ori, clp, u, out, A8, AT8, accs);
    gemm_trace_i8<<<dim3(N / 256, N / 256), 512, 0, stream>>>(A8, AT8, accs);
    finalize_kernel<<<1, 1, 0, stream>>>(accs, out);
}

// Round 8
// 410.292 us; speedup vs baseline: 2.5480x; 2.5480x over previous
//
#include <hip/hip_runtime.h>
#include <hip/hip_bf16.h>
#include <cstdint>
#include <cstddef>

#define N 4096
#define NN ((size_t)N * (size_t)N)

typedef int   int4v   __attribute__((ext_vector_type(4)));
typedef float float4v __attribute__((ext_vector_type(4)));

__device__ inline void async16(const void* g, void* lds) {
    __builtin_amdgcn_global_load_lds(
        (const __attribute__((address_space(1))) void*)g,
        (__attribute__((address_space(3))) void*)lds, 16, 0, 0);
}

// SWAR per-byte abs for packed i8 (valid for byte values in [-4,3], ours are [-2,2]):
// s = 0x01 per negative byte; m = 0xFF per negative byte; |v| = (v^m)+s.
__device__ inline unsigned absb4(unsigned v) {
    unsigned s = (v >> 7) & 0x01010101u;
    unsigned m = s * 255u;
    return (v ^ m) + s;
}
__device__ inline int4v absfrag(int4v v) {
    int4v r;
    r[0] = (int)absb4((unsigned)v[0]);
    r[1] = (int)absb4((unsigned)v[1]);
    r[2] = (int)absb4((unsigned)v[2]);
    r[3] = (int)absb4((unsigned)v[3]);
    return r;
}

// ---------------- kernel 1: FUSED mod + diag + build (A, AT only) ----------------
// Block owns the unordered tile pair {(I,J),(J,I)}, I<=J.  512 threads: half = t>>8
// selects the tile.  No Aa/ATa outputs (gemm derives |A| in-register); all 12
// float4 loads issued before any dependent store.  All expressions keep the proven
// operand order:  A[r][c] = mod[r][c] + mod[c][r] - d[c];  mod = fmaf(hard,-2o,o),
// hard = (p+u >= 1)  [bit-exact].
__global__ __launch_bounds__(512) void fused_mod_build(
        const float* __restrict__ ori,
        const float* __restrict__ clp,
        const float* __restrict__ uu,
        float* __restrict__ out,
        signed char* __restrict__ A,
        signed char* __restrict__ AT,
        double* __restrict__ accs) {
    const int I = blockIdx.x, J = blockIdx.y;
    if (I > J) return;
    __shared__ float sm1[64][65];   // sm1[i][j] = mod[bi+i][bj+j]
    __shared__ float sm2[64][65];   // sm2[j][i] = mod[bj+j][bi+i]
    __shared__ float dI[64], dJ[64];
    const int t    = threadIdx.x;   // 0..511
    const int half = t >> 8;        // 0: tile (I,J); 1: tile (J,I)
    const int tt   = t & 255;
    const int r    = tt >> 2;       // 0..63
    const int q    = tt & 3;        // 0..3 (16-col group)
    const int bi = I * 64, bj = J * 64;
    if (I == 0 && J == 0 && t < 2) accs[t] = 0.0;
    if (t < 128) {
        const int x = (t < 64) ? (bi + t) : (bj + (t - 64));
        const size_t off = (size_t)x * N + x;
        const float o = ori[off];
        const float hard = (clp[off] + uu[off] >= 1.0f) ? 1.0f : 0.0f;
        const float d = fmaf(hard, -2.0f * o, o);
        if (t < 64) dI[t] = d; else dJ[t - 64] = d;
    }
    // load phase: each half loads its own tile; all 12 loads in flight first
    {
        const int rowbase = half ? bj : bi;
        const int colbase = half ? bi : bj;
        float (*sm)[65] = half ? sm2 : sm1;
        const bool wr = (half == 0) || (I != J);   // skip duplicate out-write on diagonal
        float4v o4[4], p4[4], u4[4];
        #pragma unroll
        for (int k = 0; k < 4; ++k) {
            const size_t off = (size_t)(rowbase + r) * N + colbase + k * 16 + q * 4;
            o4[k] = *(const float4v*)(ori + off);
        }
        #pragma unroll
        for (int k = 0; k < 4; ++k) {
            const size_t off = (size_t)(rowbase + r) * N + colbase + k * 16 + q * 4;
            p4[k] = *(const float4v*)(clp + off);
        }
        #pragma unroll
        for (int k = 0; k < 4; ++k) {
            const size_t off = (size_t)(rowbase + r) * N + colbase + k * 16 + q * 4;
            u4[k] = *(const float4v*)(uu + off);
        }
        #pragma unroll
        for (int k = 0; k < 4; ++k) {
            float4v m;
            #pragma unroll
            for (int c = 0; c < 4; ++c) {
                const float hard = (p4[k][c] + u4[k][c] >= 1.0f) ? 1.0f : 0.0f;
                m[c] = fmaf(hard, -2.0f * o4[k][c], o4[k][c]);
                sm[r][k * 16 + q * 4 + c] = m[c];
            }
            if (wr) {
                const size_t off = (size_t)(rowbase + r) * N + colbase + k * 16 + q * 4;
                *(float4v*)(out + off) = m;
            }
        }
    }
    __syncthreads();
    // pack phase: half 0 emits A(I,J) + AT(J,I); half 1 emits A(J,I) + AT(I,J)
    if (half == 0) {
        int pkA1[4], pkT1[4];
        #pragma unroll
        for (int w = 0; w < 4; ++w) {
            int a1w = 0, t1w = 0;
            #pragma unroll
            for (int k = 0; k < 4; ++k) {
                const int c = q * 16 + w * 4 + k;
                const float a1 = sm1[r][c] + sm2[c][r] - dJ[c];
                const int v1 = (int)a1;
                a1w |= (v1 & 255) << (8 * k);
                const float t1 = sm1[c][r] + sm2[r][c] - dJ[r];
                const int w1 = (int)t1;
                t1w |= (w1 & 255) << (8 * k);
            }
            pkA1[w] = a1w; pkT1[w] = t1w;
        }
        const size_t oIJ = (size_t)(bi + r) * N + bj + q * 16;
        const size_t oJI = (size_t)(bj + r) * N + bi + q * 16;
        *(int4v*)&A [oIJ] = *(int4v*)pkA1;
        *(int4v*)&AT[oJI] = *(int4v*)pkT1;
    } else if (I != J) {
        int pkA2[4], pkT2[4];
        #pragma unroll
        for (int w = 0; w < 4; ++w) {
            int a2w = 0, t2w = 0;
            #pragma unroll
            for (int k = 0; k < 4; ++k) {
                const int c = q * 16 + w * 4 + k;
                const float a2 = sm2[r][c] + sm1[c][r] - dI[c];
                const int v2 = (int)a2;
                a2w |= (v2 & 255) << (8 * k);
                const float t2 = sm2[c][r] + sm1[r][c] - dI[r];
                const int w2 = (int)t2;
                t2w |= (w2 & 255) << (8 * k);
            }
            pkA2[w] = a2w; pkT2[w] = t2w;
        }
        const size_t oIJ = (size_t)(bi + r) * N + bj + q * 16;
        const size_t oJI = (size_t)(bj + r) * N + bi + q * 16;
        *(int4v*)&A [oJI] = *(int4v*)pkA2;
        *(int4v*)&AT[oIJ] = *(int4v*)pkT2;
    }
}

// ---------------- kernel 4: i8 GEMM-trace, 256x256 tile, ONE barrier per K-tile -------
// Round-3 proven schedule and register budget (single acc[8][4]).  Grid z=2:
// z=0 computes tr((A.A).A); z=1 computes tr((|A|.|A|).|A|) by applying the SWAR
// byte-abs to each fragment IN PLACE after the LDS read (block-uniform branch,
// no extra live accumulator state — round 6's double-acc spilled to scratch).
// Both slices stage the same A/AT bytes (z=1 rides the L3).
#define BK 64
#define NT (N / BK)      // 64 K-tiles
#define BUFSZ 32768      // A 16K + B 16K per buffer

__global__ __launch_bounds__(512, 2) void gemm_trace_i8(
        const signed char* __restrict__ Ag,
        const signed char* __restrict__ ATg,
        double* __restrict__ accs) {
    __shared__ __align__(16) signed char lds[4 * BUFSZ];   // 128 KiB
    __shared__ int red[8];
    const int z = blockIdx.z;
    const signed char* Asrc = Ag;    // M rows   (i-panel)
    const signed char* Bsrc = ATg;   // MT rows  (k-panel), B[k][n] = MT[n][k]
    const int i0 = blockIdx.y * 256;
    const int k0 = blockIdx.x * 256;
    const int t = threadIdx.x;
    const int lane = t & 63;
    const int wave = t >> 6;        // 0..7
    const int wm = wave >> 2;       // 0..1 -> M offset wm*128
    const int wn = wave & 3;        // 0..3 -> N offset wn*64
    const int quad = lane >> 4;
    const int col  = lane & 15;

    const int c1 = t;
    const int r1 = c1 >> 2;          // 0..127
    const int r2 = r1 + 128;
    const int s1 = (((c1 & 3) ^ ((r1 >> 1) & 3)) << 4);
    const int s2 = (((c1 & 3) ^ ((r2 >> 1) & 3)) << 4);
    const signed char* gA1 = Asrc + (size_t)(i0 + r1) * N + s1;
    const signed char* gA2 = Asrc + (size_t)(i0 + r2) * N + s2;
    const signed char* gB1 = Bsrc + (size_t)(k0 + r1) * N + s1;
    const signed char* gB2 = Bsrc + (size_t)(k0 + r2) * N + s2;
    const int ldsA1 = (wave * 64) * 16;           // wave-uniform LDS bases
    const int ldsA2 = 8192  + (wave * 64) * 16;
    const int ldsB1 = 16384 + (wave * 64) * 16;
    const int ldsB2 = 24576 + (wave * 64) * 16;
    const int fsw = ((quad ^ ((col >> 1) & 3)) << 4);  // fragment k-slot after swizzle

    int4v acc[8][4];
    #pragma unroll
    for (int a = 0; a < 8; ++a)
        #pragma unroll
        for (int b = 0; b < 4; ++b)
            acc[a][b] = (int4v){0, 0, 0, 0};

    for (int p = 0; p < 3; ++p) {
        const int pb = p * BUFSZ;
        const size_t go = (size_t)p * BK;
        async16(gA1 + go, lds + pb + ldsA1);
        async16(gA2 + go, lds + pb + ldsA2);
        async16(gB1 + go, lds + pb + ldsB1);
        async16(gB2 + go, lds + pb + ldsB2);
    }
    asm volatile("s_waitcnt vmcnt(8)" ::: "memory");
    __builtin_amdgcn_s_barrier();
    __builtin_amdgcn_sched_barrier(0);

    for (int j = 0; j < NT; ++j) {
        const int buf = (j & 3) * BUFSZ;
        const signed char* Ab = lds + buf;
        const signed char* Bb = lds + buf + 16384;
        const int pre = j + 3;
        const size_t go = (size_t)pre * BK;
        const int pb = (pre & 3) * BUFSZ;
        int4v af0[4], af1[4], bf[4];
        // issue all 12 fragment reads up front (af0+bf oldest, af1 newest)
        #pragma unroll
        for (int tr = 0; tr < 4; ++tr)
            af0[tr] = *(const int4v*)(Ab + ((wm * 128 + tr * 16 + col) << 6) + fsw);
        #pragma unroll
        for (int tc = 0; tc < 4; ++tc)
            bf[tc] = *(const int4v*)(Bb + ((wn * 64 + tc * 16 + col) << 6) + fsw);
        #pragma unroll
        for (int tr = 0; tr < 4; ++tr)
            af1[tr] = *(const int4v*)(Ab + ((wm * 128 + 64 + tr * 16 + col) << 6) + fsw);
        if (pre < NT) {
            async16(gA1 + go, lds + pb + ldsA1);
            async16(gA2 + go, lds + pb + ldsA2);
            async16(gB1 + go, lds + pb + ldsB1);
            async16(gB2 + go, lds + pb + ldsB2);
        }
        // half 0: wait af0+bf only (8 oldest of 12)
        asm volatile("s_waitcnt lgkmcnt(4)" ::: "memory");
        __builtin_amdgcn_sched_barrier(0);
        if (z) {   // block-uniform: |A| slice transforms fragments in place
            #pragma unroll
            for (int tr = 0; tr < 4; ++tr) af0[tr] = absfrag(af0[tr]);
            #pragma unroll
            for (int tc = 0; tc < 4; ++tc) bf[tc] = absfrag(bf[tc]);
        }
        __builtin_amdgcn_s_setprio(1);
        #pragma unroll
        for (int tr = 0; tr < 4; ++tr)
            #pragma unroll
            for (int tc = 0; tc < 4; ++tc)
                acc[tr][tc] = __builtin_amdgcn_mfma_i32_16x16x64_i8(af0[tr], bf[tc], acc[tr][tc], 0, 0, 0);
        __builtin_amdgcn_s_setprio(0);
        // half 1: af1 completed under the half-0 MFMA cluster
        asm volatile("s_waitcnt lgkmcnt(0)" ::: "memory");
        __builtin_amdgcn_sched_barrier(0);
        if (z) {
            #pragma unroll
            for (int tr = 0; tr < 4; ++tr) af1[tr] = absfrag(af1[tr]);
        }
        __builtin_amdgcn_s_setprio(1);
        #pragma unroll
        for (int tr = 0; tr < 4; ++tr)
            #pragma unroll
            for (int tc = 0; tc < 4; ++tc)
                acc[4 + tr][tc] = __builtin_amdgcn_mfma_i32_16x16x64_i8(af1[tr], bf[tc], acc[4 + tr][tc], 0, 0, 0);
        __builtin_amdgcn_s_setprio(0);
        // end-of-tile counted wait: tile j+1's staging landed; single barrier per tile
        if (j < NT - 3)       { asm volatile("s_waitcnt vmcnt(8)" ::: "memory"); }
        else if (j == NT - 3) { asm volatile("s_waitcnt vmcnt(4)" ::: "memory"); }
        else if (j == NT - 2) { asm volatile("s_waitcnt vmcnt(0)" ::: "memory"); }
        __builtin_amdgcn_s_barrier();
        __builtin_amdgcn_sched_barrier(0);
    }

    // trace epilogue: C/D layout col=lane&15, row=quad*4+reg.  Multiplier
    // M[k,i] = Asrc[kk*N + ib + r] (one int load), abs'd for z=1.
    int part = 0;
    #pragma unroll
    for (int mr = 0; mr < 8; ++mr) {
        const int ib = i0 + wm * 128 + mr * 16 + quad * 4;
        #pragma unroll
        for (int tc = 0; tc < 4; ++tc) {
            const int kk = k0 + wn * 64 + tc * 16 + col;
            unsigned mv = *(const unsigned*)&Asrc[(size_t)kk * N + ib];
            if (z) mv = absb4(mv);
            #pragma unroll
            for (int r = 0; r < 4; ++r)
                part += acc[mr][tc][r] * (int)(signed char)(mv >> (8 * r));
        }
    }
    #pragma unroll
    for (int off = 32; off > 0; off >>= 1)
        part += __shfl_down(part, off, 64);
    if (lane == 0) red[wave] = part;
    __syncthreads();
    if (t == 0) {
        int tot = 0;
        #pragma unroll
        for (int w = 0; w < 8; ++w) tot += red[w];
        atomicAdd(&accs[z], (double)tot);
    }
}

// ---------------- kernel 5: balance ----------------
__global__ void finalize_kernel(const double* __restrict__ accs, float* __restrict__ out) {
    out[NN] = (float)(0.5 * (1.0 + accs[0] / accs[1]));
}

extern "C" void kernel_launch(void* const* d_in, const int* in_sizes, int n_in,
                              void* d_out, int out_size, void* d_ws, size_t ws_size,
                              hipStream_t stream) {
    const float* ori = (const float*)d_in[0];
    const float* clp = (const float*)d_in[1];
    const float* u   = (const float*)d_in[2];
    float* out = (float*)d_out;
    char* ws = (char*)d_ws;
    signed char* A8  = (signed char*)ws;                    // 16 MiB
    signed char* AT8 = (signed char*)(ws + NN);             // 16 MiB
    double*      accs = (double*)(ws + 2 * NN);             // 16 B

    fused_mod_build<<<dim3(64, 64), 512, 0, stream>>>(
        ori, clp, u, out, A8, AT8, accs);
    gemm_trace_i8<<<dim3(N / 256, N / 256, 2), 512, 0, stream>>>(A8, AT8, accs);
    finalize_kernel<<<1, 1, 0, stream>>>(accs, out);
}

// Round 9
// 364.427 us; speedup vs baseline: 2.8687x; 1.1259x over previous
//
#include <hip/hip_runtime.h>
#include <hip/hip_bf16.h>
#include <cstdint>
#include <cstddef>

#define N 4096
#define NN ((size_t)N * (size_t)N)

typedef int   int4v   __attribute__((ext_vector_type(4)));
typedef float float4v __attribute__((ext_vector_type(4)));

__device__ inline void async16(const void* g, void* lds) {
    __builtin_amdgcn_global_load_lds(
        (const __attribute__((address_space(1))) void*)g,
        (__attribute__((address_space(3))) void*)lds, 16, 0, 0);
}

// SWAR per-byte abs for packed i8 (valid for byte values in [-4,3], ours are [-2,2]).
__device__ inline unsigned absb4(unsigned v) {
    unsigned s = (v >> 7) & 0x01010101u;
    unsigned m = s * 255u;
    return (v ^ m) + s;
}

// ---------------- kernel 1: mod + diag, single streaming pass ----------------
// hard = rint(sigmoid((logit(p)+logit(u))/tau)) == (p+u >= 1)  [proven bit-exact];
// out = fmaf(hard, -2o, o).  The thread whose 4-span contains the diagonal element
// of its row also writes diag[row].  Block 0 zeroes the accumulators + done-counter.
__global__ void mod_diag(const float* __restrict__ ori,
                         const float* __restrict__ clp,
                         const float* __restrict__ uu,
                         float* __restrict__ out,
                         float* __restrict__ diag,
                         double* __restrict__ accs) {
    if (blockIdx.x == 0 && threadIdx.x == 0) {
        accs[0] = 0.0; accs[1] = 0.0;
        *(unsigned*)(accs + 2) = 0u;
    }
    size_t i = ((size_t)blockIdx.x * blockDim.x + threadIdx.x) * 4;
    const float4v p4 = *(const float4v*)(clp + i);
    const float4v u4 = *(const float4v*)(uu + i);
    const float4v o4 = *(const float4v*)(ori + i);
    float4v r;
    #pragma unroll
    for (int c = 0; c < 4; ++c) {
        float hard = (p4[c] + u4[c] >= 1.0f) ? 1.0f : 0.0f;
        r[c] = fmaf(hard, -2.0f * o4[c], o4[c]);
    }
    *(float4v*)(out + i) = r;
    const int row  = (int)(i >> 12);        // / N
    const int drel = row - (int)(i & 4095); // diag col - first col of span
    if (drel >= 0 && drel < 4) diag[row] = r[drel];
}

// ---------------- kernel 2: build A, AT, |A|, |A|T from out (64x64 tiles) ----------------
// Grid (64,64), 512 threads.  Half 0 (t<256) loads tile (I,J) -> sm1 and packs
// A/Aa at (I,J); half 1 loads tile (J,I) -> sm2 and packs AT/ATa at (J,I).
// A[bi+r][bj+c] = out[bi+r][bj+c] + out[bj+c][bi+r] - diag[bj+c]   (proven order);
// AT[bj+r][bi+c] = A[bi+c][bj+r] = sm1[c][r] + sm2[r][c] - diag[bj+r].
// Aa/ATa = SWAR byte-abs of the packed words (identical integers, 4 ops/word).
__global__ __launch_bounds__(512) void build64(
        const float* __restrict__ out,
        const float* __restrict__ diag,
        signed char* __restrict__ A,
        signed char* __restrict__ AT,
        signed char* __restrict__ Aa,
        signed char* __restrict__ ATa) {
    __shared__ float sm1[64][65];   // sm1[i][j] = out[bi+i][bj+j]
    __shared__ float sm2[64][65];   // sm2[j][i] = out[bj+j][bi+i]
    __shared__ float dJ[64];
    const int I = blockIdx.x, J = blockIdx.y;
    const int bi = I * 64, bj = J * 64;
    const int t    = threadIdx.x;   // 0..511
    const int half = t >> 8;
    const int tt   = t & 255;
    const int r    = tt >> 2;       // 0..63
    const int q    = tt & 3;        // 0..3
    if (t < 64) dJ[t] = diag[bj + t];
    {
        const int rowbase = half ? bj : bi;
        const int colbase = half ? bi : bj;
        float (*sm)[65] = half ? sm2 : sm1;
        #pragma unroll
        for (int k = 0; k < 4; ++k) {
            const size_t off = (size_t)(rowbase + r) * N + colbase + k * 16 + q * 4;
            const float4v v = *(const float4v*)(out + off);
            sm[r][k * 16 + q * 4 + 0] = v[0];
            sm[r][k * 16 + q * 4 + 1] = v[1];
            sm[r][k * 16 + q * 4 + 2] = v[2];
            sm[r][k * 16 + q * 4 + 3] = v[3];
        }
    }
    __syncthreads();
    if (half == 0) {
        int pkA[4], pkAb[4];
        #pragma unroll
        for (int w = 0; w < 4; ++w) {
            int aw = 0;
            #pragma unroll
            for (int k = 0; k < 4; ++k) {
                const int c = q * 16 + w * 4 + k;
                const float a = sm1[r][c] + sm2[c][r] - dJ[c];
                const int v = (int)a;
                aw |= (v & 255) << (8 * k);
            }
            pkA[w] = aw;
            pkAb[w] = (int)absb4((unsigned)aw);
        }
        const size_t oIJ = (size_t)(bi + r) * N + bj + q * 16;
        *(int4v*)&A [oIJ] = *(int4v*)pkA;
        *(int4v*)&Aa[oIJ] = *(int4v*)pkAb;
    } else {
        int pkT[4], pkTb[4];
        #pragma unroll
        for (int w = 0; w < 4; ++w) {
            int tw = 0;
            #pragma unroll
            for (int k = 0; k < 4; ++k) {
                const int c = q * 16 + w * 4 + k;
                const float a = sm1[c][r] + sm2[r][c] - dJ[r];
                const int v = (int)a;
                tw |= (v & 255) << (8 * k);
            }
            pkT[w] = tw;
            pkTb[w] = (int)absb4((unsigned)tw);
        }
        const size_t oJI = (size_t)(bj + r) * N + bi + q * 16;
        *(int4v*)&AT [oJI] = *(int4v*)pkT;
        *(int4v*)&ATa[oJI] = *(int4v*)pkTb;
    }
}

// ---------------- kernel 3: i8 GEMM-trace, 256x256 tile, ONE barrier per K-tile -------
// EXACT round-3 proven schedule (122 us, MfmaUtil 46%): 4 LDS buffers, lookahead-3,
// 12 ds_reads up front, lgkmcnt(4)/lgkmcnt(0) halves, counted vmcnt, single barrier
// per tile.  z=0: A/AT; z=1: Aa/ATa (staged from HBM — in-register abs proved 45%
// slower in round 7).  NEW: last finishing block computes the balance (fused
// finalize via device-scope counter).
#define BK 64
#define NT (N / BK)      // 64 K-tiles
#define BUFSZ 32768      // A 16K + B 16K per buffer

__global__ __launch_bounds__(512, 2) void gemm_trace_i8(
        const signed char* __restrict__ Ag,
        const signed char* __restrict__ ATg,
        const signed char* __restrict__ Aag,
        const signed char* __restrict__ ATag,
        double* __restrict__ accs,
        float* __restrict__ outbal) {
    __shared__ __align__(16) signed char lds[4 * BUFSZ];   // 128 KiB
    __shared__ int red[8];
    const int z = blockIdx.z;
    const signed char* Asrc = z ? Aag  : Ag;    // M rows   (i-panel)
    const signed char* Bsrc = z ? ATag : ATg;   // MT rows  (k-panel), B[k][n] = MT[n][k]
    const int i0 = blockIdx.y * 256;
    const int k0 = blockIdx.x * 256;
    const int t = threadIdx.x;
    const int lane = t & 63;
    const int wave = t >> 6;        // 0..7
    const int wm = wave >> 2;       // 0..1 -> M offset wm*128
    const int wn = wave & 3;        // 0..3 -> N offset wn*64
    const int quad = lane >> 4;
    const int col  = lane & 15;

    const int c1 = t;
    const int r1 = c1 >> 2;          // 0..127
    const int r2 = r1 + 128;
    const int s1 = (((c1 & 3) ^ ((r1 >> 1) & 3)) << 4);
    const int s2 = (((c1 & 3) ^ ((r2 >> 1) & 3)) << 4);
    const signed char* gA1 = Asrc + (size_t)(i0 + r1) * N + s1;
    const signed char* gA2 = Asrc + (size_t)(i0 + r2) * N + s2;
    const signed char* gB1 = Bsrc + (size_t)(k0 + r1) * N + s1;
    const signed char* gB2 = Bsrc + (size_t)(k0 + r2) * N + s2;
    const int ldsA1 = (wave * 64) * 16;           // wave-uniform LDS bases
    const int ldsA2 = 8192  + (wave * 64) * 16;
    const int ldsB1 = 16384 + (wave * 64) * 16;
    const int ldsB2 = 24576 + (wave * 64) * 16;
    const int fsw = ((quad ^ ((col >> 1) & 3)) << 4);  // fragment k-slot after swizzle

    int4v acc[8][4];
    #pragma unroll
    for (int a = 0; a < 8; ++a)
        #pragma unroll
        for (int b = 0; b < 4; ++b)
            acc[a][b] = (int4v){0, 0, 0, 0};

    for (int p = 0; p < 3; ++p) {
        const int pb = p * BUFSZ;
        const size_t go = (size_t)p * BK;
        async16(gA1 + go, lds + pb + ldsA1);
        async16(gA2 + go, lds + pb + ldsA2);
        async16(gB1 + go, lds + pb + ldsB1);
        async16(gB2 + go, lds + pb + ldsB2);
    }
    asm volatile("s_waitcnt vmcnt(8)" ::: "memory");
    __builtin_amdgcn_s_barrier();
    __builtin_amdgcn_sched_barrier(0);

    for (int j = 0; j < NT; ++j) {
        const int buf = (j & 3) * BUFSZ;
        const signed char* Ab = lds + buf;
        const signed char* Bb = lds + buf + 16384;
        const int pre = j + 3;
        const size_t go = (size_t)pre * BK;
        const int pb = (pre & 3) * BUFSZ;
        int4v af0[4], af1[4], bf[4];
        // issue all 12 fragment reads up front (af0+bf oldest, af1 newest)
        #pragma unroll
        for (int tr = 0; tr < 4; ++tr)
            af0[tr] = *(const int4v*)(Ab + ((wm * 128 + tr * 16 + col) << 6) + fsw);
        #pragma unroll
        for (int tc = 0; tc < 4; ++tc)
            bf[tc] = *(const int4v*)(Bb + ((wn * 64 + tc * 16 + col) << 6) + fsw);
        #pragma unroll
        for (int tr = 0; tr < 4; ++tr)
            af1[tr] = *(const int4v*)(Ab + ((wm * 128 + 64 + tr * 16 + col) << 6) + fsw);
        if (pre < NT) {
            async16(gA1 + go, lds + pb + ldsA1);
            async16(gA2 + go, lds + pb + ldsA2);
            async16(gB1 + go, lds + pb + ldsB1);
            async16(gB2 + go, lds + pb + ldsB2);
        }
        // half 0: wait af0+bf only (8 oldest of 12)
        asm volatile("s_waitcnt lgkmcnt(4)" ::: "memory");
        __builtin_amdgcn_sched_barrier(0);
        __builtin_amdgcn_s_setprio(1);
        #pragma unroll
        for (int tr = 0; tr < 4; ++tr)
            #pragma unroll
            for (int tc = 0; tc < 4; ++tc)
                acc[tr][tc] = __builtin_amdgcn_mfma_i32_16x16x64_i8(af0[tr], bf[tc], acc[tr][tc], 0, 0, 0);
        __builtin_amdgcn_s_setprio(0);
        // half 1: af1 completed under the half-0 MFMA cluster
        asm volatile("s_waitcnt lgkmcnt(0)" ::: "memory");
        __builtin_amdgcn_sched_barrier(0);
        __builtin_amdgcn_s_setprio(1);
        #pragma unroll
        for (int tr = 0; tr < 4; ++tr)
            #pragma unroll
            for (int tc = 0; tc < 4; ++tc)
                acc[4 + tr][tc] = __builtin_amdgcn_mfma_i32_16x16x64_i8(af1[tr], bf[tc], acc[4 + tr][tc], 0, 0, 0);
        __builtin_amdgcn_s_setprio(0);
        // end-of-tile counted wait: tile j+1's staging landed; single barrier per tile
        if (j < NT - 3)       { asm volatile("s_waitcnt vmcnt(8)" ::: "memory"); }
        else if (j == NT - 3) { asm volatile("s_waitcnt vmcnt(4)" ::: "memory"); }
        else if (j == NT - 2) { asm volatile("s_waitcnt vmcnt(0)" ::: "memory"); }
        __builtin_amdgcn_s_barrier();
        __builtin_amdgcn_sched_barrier(0);
    }

    // trace epilogue: C/D layout col=lane&15, row=quad*4+reg.
    int part = 0;
    #pragma unroll
    for (int mr = 0; mr < 8; ++mr) {
        const int ib = i0 + wm * 128 + mr * 16 + quad * 4;
        #pragma unroll
        for (int tc = 0; tc < 4; ++tc) {
            const int kk = k0 + wn * 64 + tc * 16 + col;
            const int mv = *(const int*)&Bsrc[(size_t)(i0 + wm * 128 + mr * 16 + quad * 4) * 0 + 0] * 0
                         + *(const int*)&Asrc[(size_t)kk * N + ib];
            #pragma unroll
            for (int r = 0; r < 4; ++r)
                part += acc[mr][tc][r] * (int)(signed char)(mv >> (8 * r));
        }
    }
    #pragma unroll
    for (int off = 32; off > 0; off >>= 1)
        part += __shfl_down(part, off, 64);
    if (lane == 0) red[wave] = part;
    __syncthreads();
    if (t == 0) {
        int tot = 0;
        #pragma unroll
        for (int w = 0; w < 8; ++w) tot += red[w];
        atomicAdd(&accs[z], (double)tot);
        __threadfence();
        unsigned* cnt = (unsigned*)(accs + 2);
        const unsigned old = atomicAdd(cnt, 1u);
        if (old == 2u * (N / 256) * (N / 256) - 1u) {   // last of 512 blocks
            __threadfence();
            outbal[NN] = (float)(0.5 * (1.0 + accs[0] / accs[1]));
        }
    }
}

extern "C" void kernel_launch(void* const* d_in, const int* in_sizes, int n_in,
                              void* d_out, int out_size, void* d_ws, size_t ws_size,
                              hipStream_t stream) {
    const float* ori = (const float*)d_in[0];
    const float* clp = (const float*)d_in[1];
    const float* u   = (const float*)d_in[2];
    float* out = (float*)d_out;
    char* ws = (char*)d_ws;
    signed char* A8   = (signed char*)ws;                    // 16 MiB
    signed char* AT8  = (signed char*)(ws + NN);             // 16 MiB
    signed char* Aa8  = (signed char*)(ws + 2 * NN);         // 16 MiB
    signed char* ATa8 = (signed char*)(ws + 3 * NN);         // 16 MiB
    float*       diag = (float*)(ws + 4 * NN);               // 16 KiB
    double*      accs = (double*)(ws + 4 * NN + 4096 * 4);   // accs[0..1] + counter

    mod_diag<<<dim3((unsigned)(NN / 1024)), 256, 0, stream>>>(ori, clp, u, out, diag, accs);
    build64<<<dim3(64, 64), 512, 0, stream>>>(out, diag, A8, AT8, Aa8, ATa8);
    gemm_trace_i8<<<dim3(N / 256, N / 256, 2), 512, 0, stream>>>(A8, AT8, Aa8, ATa8, accs, out);
}